// Round 6
// baseline (632.898 us; speedup 1.0000x reference)
//
#include <hip/hip_runtime.h>

typedef unsigned short u16;
typedef unsigned int   u32;
typedef _Float16 f16;
typedef f16 h2 __attribute__((ext_vector_type(2)));
typedef f16 h4 __attribute__((ext_vector_type(4)));
typedef f16 h8 __attribute__((ext_vector_type(8)));

#define T_    120
#define D_    64
#define DOUT_ 31
#define KROW_ 68    // f16/row: 136B, 8B-aligned for h4 reads
#define VROW_ 132   // f16/row: 264B, 8B-aligned for h4 reads

#if defined(__has_builtin)
#if __has_builtin(__builtin_amdgcn_fdot2)
#define DOT2(a,b,c) __builtin_amdgcn_fdot2((a),(b),(c),false)
#endif
#endif
#ifndef DOT2
#define DOT2(a,b,c) ((float)(a).x*(float)(b).x + ((float)(a).y*(float)(b).y + (c)))
#endif
#define SHV(x,i,j) __builtin_shufflevector((x),(x),(i),(j))

__device__ __forceinline__ h2 pk(float a, float b){
#if defined(__has_builtin) && __has_builtin(__builtin_amdgcn_cvt_pkrtz)
  return __builtin_bit_cast(h2, __builtin_amdgcn_cvt_pkrtz(a, b));
#else
  h2 r; r.x = (f16)a; r.y = (f16)b; return r;
#endif
}
__device__ __forceinline__ float b2f(u16 u){ return __uint_as_float(((u32)u) << 16); }
__device__ __forceinline__ float2 bp2(u32 u){
  float2 r; r.x = __uint_as_float(u << 16); r.y = __uint_as_float(u & 0xffff0000u); return r;
}
__device__ __forceinline__ u16 f2bu(float f){
  u32 u = __float_as_uint(f);
  u32 r = u + 0x7fffu + ((u >> 16) & 1u);
  return (u16)(r >> 16);
}
// single-wave LDS handoff: DS pipe is in-order per wave; fence + sched barrier only
#define WSYNC() do{ __asm__ __volatile__("" ::: "memory"); __builtin_amdgcn_wave_barrier(); }while(0)

__device__ __forceinline__ float dpp_sum(float x){
  int t;
  t = __builtin_amdgcn_update_dpp(0, __float_as_int(x), 0x111, 0xf, 0xf, true); x += __int_as_float(t);
  t = __builtin_amdgcn_update_dpp(0, __float_as_int(x), 0x112, 0xf, 0xf, true); x += __int_as_float(t);
  t = __builtin_amdgcn_update_dpp(0, __float_as_int(x), 0x114, 0xf, 0xf, true); x += __int_as_float(t);
  t = __builtin_amdgcn_update_dpp(0, __float_as_int(x), 0x118, 0xf, 0xf, true); x += __int_as_float(t);
  t = __builtin_amdgcn_update_dpp(0, __float_as_int(x), 0x142, 0xf, 0xf, true); x += __int_as_float(t);
  t = __builtin_amdgcn_update_dpp(0, __float_as_int(x), 0x143, 0xf, 0xf, true); x += __int_as_float(t);
  return __int_as_float(__builtin_amdgcn_readlane(__float_as_int(x), 63));
}
__device__ __forceinline__ float dpp_max_pos(float x){   // requires true max > 0
  int t;
  t = __builtin_amdgcn_update_dpp(0, __float_as_int(x), 0x111, 0xf, 0xf, true); x = fmaxf(x, __int_as_float(t));
  t = __builtin_amdgcn_update_dpp(0, __float_as_int(x), 0x112, 0xf, 0xf, true); x = fmaxf(x, __int_as_float(t));
  t = __builtin_amdgcn_update_dpp(0, __float_as_int(x), 0x114, 0xf, 0xf, true); x = fmaxf(x, __int_as_float(t));
  t = __builtin_amdgcn_update_dpp(0, __float_as_int(x), 0x118, 0xf, 0xf, true); x = fmaxf(x, __int_as_float(t));
  t = __builtin_amdgcn_update_dpp(0, __float_as_int(x), 0x142, 0xf, 0xf, true); x = fmaxf(x, __int_as_float(t));
  t = __builtin_amdgcn_update_dpp(0, __float_as_int(x), 0x143, 0xf, 0xf, true); x = fmaxf(x, __int_as_float(t));
  return __int_as_float(__builtin_amdgcn_readlane(__float_as_int(x), 63));
}
__device__ __forceinline__ float pe_val(int row, int i){
  const float coef = -0.28782313662425574f; // -ln(10000)/32
  int p = row % 10;
  float dv  = __expf((float)(i >> 1) * coef);
  float ang = (float)p * dv;
  return (i & 1) ? __cosf(ang) : __sinf(ang);
}
__device__ __forceinline__ void loadrow32(h2* dst, const float* row){
  #pragma unroll
  for (int r = 0; r < 16; ++r){
    float4 f = ((const float4*)row)[r];
    dst[2*r]   = pk(f.x, f.y);
    dst[2*r+1] = pk(f.z, f.w);
  }
}

// ---------- kernel PRE: blocks 0-119: mem[t]+cross[t]; block 120: bf16 prep ----------
__global__ __launch_bounds__(256) void k_pre(const float* __restrict__ audio,
                                             const float* __restrict__ Wa, const float* __restrict__ ba,
                                             const float* __restrict__ Wv2, const float* __restrict__ bv2,
                                             const float* __restrict__ Wo2, const float* __restrict__ bo2,
                                             const float* __restrict__ Wo, const float* __restrict__ W1,
                                             const float* __restrict__ W2, const float* __restrict__ Wr,
                                             float* __restrict__ cross,
                                             u16* __restrict__ wob, u16* __restrict__ w1b,
                                             u16* __restrict__ w2b, u16* __restrict__ wrb){
  const int b = blockIdx.x, tid = threadIdx.x;
  if (b == 120){
    for (int i = tid; i < 4096; i += 256) wob[i] = f2bu(Wo[i]);
    for (int i = tid; i < 8192; i += 256){ w1b[i] = f2bu(W1[i]); w2b[i] = f2bu(W2[i]); }
    for (int i = tid; i < 1984; i += 256) wrb[i] = f2bu(Wr[i]);
    return;
  }
  __shared__ float ash[1024];
  __shared__ float msh[64], tsh[64];
  for (int i = tid; i < 1024; i += 256) ash[i] = audio[b*1024 + i];
  __syncthreads();
  const int w = tid >> 6, lane = tid & 63;
  for (int d = w*16; d < w*16 + 16; ++d){
    const float4* row = (const float4*)(Wa + d*1024);
    float acc = 0.f;
    #pragma unroll
    for (int m = 0; m < 4; ++m){
      float4 wp = row[lane + 64*m];
      int j = 4*(lane + 64*m);
      acc += wp.x*ash[j] + wp.y*ash[j+1] + wp.z*ash[j+2] + wp.w*ash[j+3];
    }
    acc = dpp_sum(acc);
    if (lane == 0) msh[d] = acc + ba[d];
  }
  __syncthreads();
  if (tid < 64){
    const float4* r1 = (const float4*)(Wv2 + tid*64);
    float a = bv2[tid];
    #pragma unroll
    for (int j = 0; j < 16; ++j){ float4 p = r1[j]; a += p.x*msh[4*j] + p.y*msh[4*j+1] + p.z*msh[4*j+2] + p.w*msh[4*j+3]; }
    tsh[tid] = a;
  }
  __syncthreads();
  if (tid < 64){
    const float4* r2 = (const float4*)(Wo2 + tid*64);
    float c = bo2[tid];
    #pragma unroll
    for (int j = 0; j < 16; ++j){ float4 p = r2[j]; c += p.x*tsh[4*j] + p.y*tsh[4*j+1] + p.z*tsh[4*j+2] + p.w*tsh[4*j+3]; }
    cross[b*64 + tid] = c;
  }
}

// ---------- kernel SCAN: single wave (64 threads), zero barriers, all weights in VGPRs ----------
__global__ __launch_bounds__(64, 1) void k_scan(
    const float* __restrict__ objW,
    const float* __restrict__ Wq, const float* __restrict__ bq,
    const float* __restrict__ Wk, const float* __restrict__ bk,
    const float* __restrict__ Wv, const float* __restrict__ bv,
    const float* __restrict__ Wo, const float* __restrict__ bo,
    const float* __restrict__ g1, const float* __restrict__ be1,
    const float* __restrict__ g2, const float* __restrict__ be2,
    const float* __restrict__ g3, const float* __restrict__ be3,
    const float* __restrict__ W1, const float* __restrict__ c1,
    const float* __restrict__ W2, const float* __restrict__ c2,
    const float* __restrict__ Wr, const float* __restrict__ br,
    const float* __restrict__ Wm, const float* __restrict__ bm,
    const float* __restrict__ cross,
    float* __restrict__ xw, float* __restrict__ Kw, float* __restrict__ Vw)
{
  __shared__ __align__(16) f16 KcS[128*KROW_];  // 17.0 KB, rows 119..127 stay zero
  __shared__ __align__(16) f16 VcS[D_*VROW_];   // 16.5 KB
  __shared__ __align__(16) f16 sch[256];        // [head][128], zero-padded
  __shared__ __align__(16) f16 xh[64], qh[64], ath[64], h2h[64], h3h[64], rsh[32];
  __shared__ __align__(16) h2  fsh2[64];        // (f_k, f_{k+64}) pairs
  __shared__ float pe_tab[640];

  const int i = threadIdx.x;   // 0..63, one wave

  // ---- register-resident weights (f16 pairs) ----
  h2 WQ[32], WK[32], WV[32], WOr[32], W1a[32], W1b[32], WRr[32], WMr[16];
  h2 W2r[64];                  // interleaved columns (k, k+64)

  loadrow32(WQ,  Wq + i*64);
  loadrow32(WK,  Wk + i*64);
  loadrow32(WV,  Wv + i*64);
  loadrow32(WOr, Wo + i*64);
  loadrow32(W1a, W1 + i*64);
  loadrow32(W1b, W1 + (64+i)*64);
  {
    const float4* ra = (const float4*)(W2 + i*128);
    const float4* rb = (const float4*)(W2 + i*128 + 64);
    #pragma unroll
    for (int r = 0; r < 16; ++r){
      float4 a = ra[r], b = rb[r];
      W2r[4*r+0] = pk(a.x, b.x); W2r[4*r+1] = pk(a.y, b.y);
      W2r[4*r+2] = pk(a.z, b.z); W2r[4*r+3] = pk(a.w, b.w);
    }
  }
  loadrow32(WRr, Wr + (i < 31 ? i : 30)*64);
  {
    const float* row = Wm + i*31;
    #pragma unroll
    for (int r = 0; r < 15; ++r) WMr[r] = pk(row[2*r], row[2*r+1]);
    WMr[15] = pk(row[30], 0.f);
  }
  const float bq_r = bq[i], bk_r = bk[i], bv_r = bv[i], bo_r = bo[i];
  const float c1a = c1[i], c1b = c1[64+i], c2_r = c2[i];
  const float br_r = (i < 31) ? br[i] : 0.f;
  const float st = objW[i*5];
  const float bmst = bm[i] + st;
  const float cls_r = cross[119*64 + i];
  const float g1r = g1[i], b1r = be1[i], g2r = g2[i], b2r = be2[i], g3r = g3[i], b3r = be3[i];

  { u32* p = (u32*)KcS; for (int idx = i; idx < 128*KROW_/2; idx += 64) p[idx] = 0; }
  { u32* p = (u32*)VcS; for (int idx = i; idx < D_*VROW_/2;  idx += 64) p[idx] = 0; }
  for (int idx = i; idx < 640; idx += 64) pe_tab[idx] = pe_val(idx >> 6, idx & 63);
  if (i < 32) rsh[i] = (f16)0.f;

  float xr = st + pe_val(0, i);
  xh[i] = (f16)xr;
  xw[i] = xr;
  WSYNC();

  int pp = 1;  // (t+1) % 10
  for (int t = 0; t < T_-1; ++t){
    // ---- P1: q, k, v from x_t ----
    {
      const h8* xv = (const h8*)xh;
      float q0=bq_r,q1=0.f,q2=0.f,q3=0.f, k0=bk_r,k1=0.f,k2=0.f,k3=0.f, v0=bv_r,v1=0.f,v2=0.f,v3=0.f;
      #pragma unroll
      for (int r = 0; r < 8; ++r){
        h8 x = xv[r];
        h2 xa=SHV(x,0,1), xb=SHV(x,2,3), xc=SHV(x,4,5), xd=SHV(x,6,7);
        q0 = DOT2(WQ[4*r+0], xa, q0); q1 = DOT2(WQ[4*r+1], xb, q1);
        q2 = DOT2(WQ[4*r+2], xc, q2); q3 = DOT2(WQ[4*r+3], xd, q3);
        k0 = DOT2(WK[4*r+0], xa, k0); k1 = DOT2(WK[4*r+1], xb, k1);
        k2 = DOT2(WK[4*r+2], xc, k2); k3 = DOT2(WK[4*r+3], xd, k3);
        v0 = DOT2(WV[4*r+0], xa, v0); v1 = DOT2(WV[4*r+1], xb, v1);
        v2 = DOT2(WV[4*r+2], xc, v2); v3 = DOT2(WV[4*r+3], xd, v3);
      }
      float q = (q0+q1)+(q2+q3), k = (k0+k1)+(k2+k3), v = (v0+v1)+(v2+v3);
      qh[i] = (f16)q;
      KcS[t*KROW_ + i] = (f16)k;
      VcS[i*VROW_ + t] = (f16)v;
      Kw[t*64 + i] = k;           // fire-and-forget (never drained in-loop)
      Vw[t*64 + i] = v;
    }
    WSYNC();
    // ---- P2+P3: lane j scores positions j and j+64, BOTH heads; softmax via DPP ----
    {
      const int j = i;
      const h8* qv = (const h8*)qh;                       // uniform broadcast reads
      const h4* kr0 = (const h4*)(KcS + j*KROW_);
      const h4* kr1 = (const h4*)(KcS + (j+64)*KROW_);
      float a00=0.f,b00=0.f,a01=0.f,b01=0.f,a10=0.f,b10=0.f,a11=0.f,b11=0.f;
      #pragma unroll
      for (int r = 0; r < 4; ++r){
        h8 qlo = qv[r], qhi = qv[4+r];
        h2 ql0=SHV(qlo,0,1), ql1=SHV(qlo,2,3), ql2=SHV(qlo,4,5), ql3=SHV(qlo,6,7);
        h2 qh0=SHV(qhi,0,1), qh1=SHV(qhi,2,3), qh2=SHV(qhi,4,5), qh3=SHV(qhi,6,7);
        h4 ka = kr0[2*r], kb = kr0[2*r+1];     // row j, head0 half
        h4 kc = kr0[8+2*r], kd = kr0[9+2*r];   // row j, head1 half
        h4 ke = kr1[2*r], kf = kr1[2*r+1];     // row j+64, head0 half
        h4 kg = kr1[8+2*r], kh = kr1[9+2*r];   // row j+64, head1 half
        a00 = DOT2(SHV(ka,0,1), ql0, a00); b00 = DOT2(SHV(ka,2,3), ql1, b00);
        a00 = DOT2(SHV(kb,0,1), ql2, a00); b00 = DOT2(SHV(kb,2,3), ql3, b00);
        a10 = DOT2(SHV(kc,0,1), qh0, a10); b10 = DOT2(SHV(kc,2,3), qh1, b10);
        a10 = DOT2(SHV(kd,0,1), qh2, a10); b10 = DOT2(SHV(kd,2,3), qh3, b10);
        a01 = DOT2(SHV(ke,0,1), ql0, a01); b01 = DOT2(SHV(ke,2,3), ql1, b01);
        a01 = DOT2(SHV(kf,0,1), ql2, a01); b01 = DOT2(SHV(kf,2,3), ql3, b01);
        a11 = DOT2(SHV(kg,0,1), qh0, a11); b11 = DOT2(SHV(kg,2,3), qh1, b11);
        a11 = DOT2(SHV(kh,0,1), qh2, a11); b11 = DOT2(SHV(kh,2,3), qh3, b11);
      }
      float d00 = a00+b00, d01 = a01+b01, d10 = a10+b10, d11 = a11+b11;
      const float SC = 0.17677669529663687f;
      int r0 = (t - j) / 10, r1 = (t - j - 64) / 10;
      bool m0v = (j <= t), m1v = (j + 64 <= t);
      float s00 = m0v ? d00*SC - 0.0625f*(float)r0      : -1e30f;
      float s01 = m1v ? d01*SC - 0.0625f*(float)r1      : -1e30f;
      float s10 = m0v ? d10*SC - 0.00390625f*(float)r0  : -1e30f;
      float s11 = m1v ? d11*SC - 0.00390625f*(float)r1  : -1e30f;
      float mx0 = dpp_max_pos(fmaxf(s00, s01) + 16384.f) - 16384.f;
      float mx1 = dpp_max_pos(fmaxf(s10, s11) + 16384.f) - 16384.f;
      float e00 = m0v ? __expf(s00 - mx0) : 0.f;
      float e01 = m1v ? __expf(s01 - mx0) : 0.f;
      float e10 = m0v ? __expf(s10 - mx1) : 0.f;
      float e11 = m1v ? __expf(s11 - mx1) : 0.f;
      float inv0 = 1.f / dpp_sum(e00 + e01);
      float inv1 = 1.f / dpp_sum(e10 + e11);
      sch[j]        = (f16)(e00*inv0);
      sch[j+64]     = (f16)(e01*inv0);
      sch[128+j]    = (f16)(e10*inv1);
      sch[128+j+64] = (f16)(e11*inv1);
    }
    WSYNC();
    // ---- P4: attn out for dim i (head = i>>5), full 120 positions ----
    float atv;
    {
      const h8* av = (const h8*)(sch + (i >> 5)*128);   // 2 distinct addrs -> broadcast
      const h4* vv = (const h4*)(VcS + i*VROW_);
      float p0=0.f,p1=0.f,p2=0.f,p3=0.f;
      #pragma unroll
      for (int r = 0; r < 15; ++r){
        h8 a = av[r];
        h4 va = vv[2*r], vb = vv[2*r+1];
        p0 = DOT2(SHV(va,0,1), SHV(a,0,1), p0);
        p1 = DOT2(SHV(va,2,3), SHV(a,2,3), p1);
        p2 = DOT2(SHV(vb,0,1), SHV(a,4,5), p2);
        p3 = DOT2(SHV(vb,2,3), SHV(a,6,7), p3);
      }
      atv = (p0+p1)+(p2+p3);
      ath[i] = (f16)atv;
    }
    WSYNC();
    // ---- P5: sa = at@Wo^T + bo ; LN1 ; +cross_last ; LN2 ----
    float h2v;
    {
      const h8* av = (const h8*)ath;
      float a0=bo_r, a1=0.f, a2=0.f, a3=0.f;
      #pragma unroll
      for (int r = 0; r < 8; ++r){
        h8 x = av[r];
        a0 = DOT2(WOr[4*r+0], SHV(x,0,1), a0);
        a1 = DOT2(WOr[4*r+1], SHV(x,2,3), a1);
        a2 = DOT2(WOr[4*r+2], SHV(x,4,5), a2);
        a3 = DOT2(WOr[4*r+3], SHV(x,6,7), a3);
      }
      float y = xr + (a0+a1)+(a2+a3);
      float s = dpp_sum(y), s2 = dpp_sum(y*y);
      float m = s*(1.f/64.f), var = fmaxf(s2*(1.f/64.f) - m*m, 0.f);
      float h1 = (y - m)*rsqrtf(var + 1e-5f)*g1r + b1r;
      float z = h1 + cls_r;
      float sz = dpp_sum(z), sz2 = dpp_sum(z*z);
      float mz = sz*(1.f/64.f), vz = fmaxf(sz2*(1.f/64.f) - mz*mz, 0.f);
      h2v = (z - mz)*rsqrtf(vz + 1e-5f)*g2r + b2r;
      h2h[i] = (f16)h2v;
    }
    WSYNC();
    // ---- P6: FFN1, rows i and i+64 ----
    {
      const h8* hv = (const h8*)h2h;
      float a0=c1a, a1=0.f, a2=0.f, a3=0.f, b0=c1b, b1=0.f, b2=0.f, b3=0.f;
      #pragma unroll
      for (int r = 0; r < 8; ++r){
        h8 x = hv[r];
        h2 xa=SHV(x,0,1), xb=SHV(x,2,3), xc=SHV(x,4,5), xd=SHV(x,6,7);
        a0 = DOT2(W1a[4*r+0], xa, a0); a1 = DOT2(W1a[4*r+1], xb, a1);
        a2 = DOT2(W1a[4*r+2], xc, a2); a3 = DOT2(W1a[4*r+3], xd, a3);
        b0 = DOT2(W1b[4*r+0], xa, b0); b1 = DOT2(W1b[4*r+1], xb, b1);
        b2 = DOT2(W1b[4*r+2], xc, b2); b3 = DOT2(W1b[4*r+3], xd, b3);
      }
      float fa = fmaxf((a0+a1)+(a2+a3), 0.f);
      float fb = fmaxf((b0+b1)+(b2+b3), 0.f);
      fsh2[i] = pk(fa, fb);
    }
    WSYNC();
    // ---- P7: FFN2 (interleaved pairs) + LN3 ----
    float h3v;
    {
      const h8* fv = (const h8*)fsh2;
      float a0=c2_r, a1=0.f, a2=0.f, a3=0.f;
      #pragma unroll
      for (int r = 0; r < 16; ++r){
        h8 x = fv[r];
        a0 = DOT2(W2r[4*r+0], SHV(x,0,1), a0);
        a1 = DOT2(W2r[4*r+1], SHV(x,2,3), a1);
        a2 = DOT2(W2r[4*r+2], SHV(x,4,5), a2);
        a3 = DOT2(W2r[4*r+3], SHV(x,6,7), a3);
      }
      float y = h2v + (a0+a1)+(a2+a3);
      float s = dpp_sum(y), s2 = dpp_sum(y*y);
      float m = s*(1.f/64.f), var = fmaxf(s2*(1.f/64.f) - m*m, 0.f);
      h3v = (y - m)*rsqrtf(var + 1e-5f)*g3r + b3r;
      h3h[i] = (f16)h3v;
    }
    WSYNC();
    // ---- P8: r = h3@Wr^T + br ----
    {
      const h8* hv = (const h8*)h3h;
      float r0=br_r, r1=0.f, r2=0.f, r3=0.f;
      #pragma unroll
      for (int r = 0; r < 8; ++r){
        h8 x = hv[r];
        r0 = DOT2(WRr[4*r+0], SHV(x,0,1), r0);
        r1 = DOT2(WRr[4*r+1], SHV(x,2,3), r1);
        r2 = DOT2(WRr[4*r+2], SHV(x,4,5), r2);
        r3 = DOT2(WRr[4*r+3], SHV(x,6,7), r3);
      }
      if (i < DOUT_) rsh[i] = (f16)((r0+r1)+(r2+r3));
    }
    WSYNC();
    // ---- P9: new = r@Wm^T + bm + style + pe ----
    {
      const h8* rv = (const h8*)rsh;
      float m0=bmst, m1=0.f, m2=0.f, m3=0.f;
      #pragma unroll
      for (int r = 0; r < 4; ++r){
        h8 x = rv[r];
        m0 = DOT2(WMr[4*r+0], SHV(x,0,1), m0);
        m1 = DOT2(WMr[4*r+1], SHV(x,2,3), m1);
        m2 = DOT2(WMr[4*r+2], SHV(x,4,5), m2);
        m3 = DOT2(WMr[4*r+3], SHV(x,6,7), m3);
      }
      float xn = (m0+m1)+(m2+m3) + pe_tab[pp*64 + i];
      xr = xn;
      xh[i] = (f16)xn;
      xw[(t+1)*64 + i] = xn;
    }
    WSYNC();
    pp = (pp == 9) ? 0 : pp + 1;
  }
  // ---- epilogue: k, v for row 119 ----
  {
    const h8* xv = (const h8*)xh;
    float k0=bk_r,k1=0.f,k2=0.f,k3=0.f, v0=bv_r,v1=0.f,v2=0.f,v3=0.f;
    #pragma unroll
    for (int r = 0; r < 8; ++r){
      h8 x = xv[r];
      h2 xa=SHV(x,0,1), xb=SHV(x,2,3), xc=SHV(x,4,5), xd=SHV(x,6,7);
      k0 = DOT2(WK[4*r+0], xa, k0); k1 = DOT2(WK[4*r+1], xb, k1);
      k2 = DOT2(WK[4*r+2], xc, k2); k3 = DOT2(WK[4*r+3], xd, k3);
      v0 = DOT2(WV[4*r+0], xa, v0); v1 = DOT2(WV[4*r+1], xb, v1);
      v2 = DOT2(WV[4*r+2], xc, v2); v3 = DOT2(WV[4*r+3], xd, v3);
    }
    Kw[119*64 + i] = (k0+k1)+(k2+k3);
    Vw[119*64 + i] = (v0+v1)+(v2+v3);
  }
}

// ---------- kernel FINAL: full pass, one block per row ----------
__global__ __launch_bounds__(128) void k_final(
    const float* __restrict__ Wq, const float* __restrict__ bq, const float* __restrict__ bo,
    const float* __restrict__ g1, const float* __restrict__ be1,
    const float* __restrict__ g2, const float* __restrict__ be2,
    const float* __restrict__ g3, const float* __restrict__ be3,
    const float* __restrict__ c1, const float* __restrict__ c2, const float* __restrict__ br,
    const u16* __restrict__ wo_b, const u16* __restrict__ w1_b,
    const u16* __restrict__ w2_b, const u16* __restrict__ wr_b,
    const float* __restrict__ cross, const float* __restrict__ xw,
    const float* __restrict__ Kw, const float* __restrict__ Vw,
    float* __restrict__ out)
{
  __shared__ float xs[64], qs[64], at[64], h2s[64], h3s[64], fs[128], sc[256];
  const int irow = blockIdx.x, tid = threadIdx.x;
  if (tid < 64) xs[tid] = xw[irow*64 + tid];
  __syncthreads();
  if (tid < 64){
    const float4* wr_ = (const float4*)(Wq + tid*64);
    float acc = bq[tid];
    #pragma unroll
    for (int j = 0; j < 16; ++j){ float4 w = wr_[j]; acc += w.x*xs[4*j] + w.y*xs[4*j+1] + w.z*xs[4*j+2] + w.w*xs[4*j+3]; }
    qs[tid] = acc;
  }
  __syncthreads();
  {
    const int h = tid >> 6, j = tid & 63;
    const float* qh_ = qs + h*32;
    float d0 = 0.f, d1 = 0.f;
    const float4* k0 = (const float4*)(Kw + j*64 + h*32);
    #pragma unroll
    for (int w = 0; w < 8; ++w){ float4 p = k0[w]; d0 += p.x*qh_[4*w] + p.y*qh_[4*w+1] + p.z*qh_[4*w+2] + p.w*qh_[4*w+3]; }
    if (j < 56){
      const float4* k1 = (const float4*)(Kw + (j+64)*64 + h*32);
      #pragma unroll
      for (int w = 0; w < 8; ++w){ float4 p = k1[w]; d1 += p.x*qh_[4*w] + p.y*qh_[4*w+1] + p.z*qh_[4*w+2] + p.w*qh_[4*w+3]; }
    }
    const float slope = h ? 0.00390625f : 0.0625f;
    float s0 = (j      <= irow) ? d0*0.17677669529663687f - slope*(float)((irow-j)/10)    : -1e30f;
    float s1 = (j + 64 <= irow) ? d1*0.17677669529663687f - slope*(float)((irow-j-64)/10) : -1e30f;
    float m = dpp_max_pos(fmaxf(s0, s1) + 16384.f) - 16384.f;
    float e0 = (j      <= irow) ? __expf(s0 - m) : 0.f;
    float e1 = (j + 64 <= irow) ? __expf(s1 - m) : 0.f;
    float inv = 1.f / dpp_sum(e0 + e1);
    sc[h*128 + j]      = e0*inv;
    sc[h*128 + j + 64] = e1*inv;
  }
  __syncthreads();
  if (tid < 64){
    const float* a = sc + (tid >> 5)*128;
    float a0=0.f,a1=0.f,a2=0.f,a3=0.f;
    #pragma unroll
    for (int jj = 0; jj < 30; ++jj){
      a0 += a[4*jj]   * Vw[(4*jj)*64   + tid];
      a1 += a[4*jj+1] * Vw[(4*jj+1)*64 + tid];
      a2 += a[4*jj+2] * Vw[(4*jj+2)*64 + tid];
      a3 += a[4*jj+3] * Vw[(4*jj+3)*64 + tid];
    }
    at[tid] = (a0+a1)+(a2+a3);
  }
  __syncthreads();
  if (tid < 64){
    const u32* orow = (const u32*)(wo_b + tid*64);
    float acc = bo[tid];
    #pragma unroll
    for (int w = 0; w < 32; ++w){ float2 p = bp2(orow[w]); acc += p.x*at[2*w] + p.y*at[2*w+1]; }
    float y = xs[tid] + acc;
    float s = dpp_sum(y), s2 = dpp_sum(y*y);
    float m = s*(1.f/64.f), var = fmaxf(s2*(1.f/64.f) - m*m, 0.f);
    float h1 = (y - m)*rsqrtf(var + 1e-5f)*g1[tid] + be1[tid];
    float z = h1 + cross[irow*64 + tid];
    float sz = dpp_sum(z), sz2 = dpp_sum(z*z);
    float mz = sz*(1.f/64.f), vz = fmaxf(sz2*(1.f/64.f) - mz*mz, 0.f);
    h2s[tid] = (z - mz)*rsqrtf(vz + 1e-5f)*g2[tid] + be2[tid];
  }
  __syncthreads();
  {
    const u32* w1r = (const u32*)(w1_b + tid*64);
    float acc = c1[tid];
    #pragma unroll
    for (int w = 0; w < 32; ++w){ float2 p = bp2(w1r[w]); acc += p.x*h2s[2*w] + p.y*h2s[2*w+1]; }
    fs[tid] = fmaxf(acc, 0.f);
  }
  __syncthreads();
  if (tid < 64){
    const u32* w2r = (const u32*)(w2_b + tid*128);
    float acc = c2[tid];
    #pragma unroll
    for (int w = 0; w < 64; ++w){ float2 p = bp2(w2r[w]); acc += p.x*fs[2*w] + p.y*fs[2*w+1]; }
    float y = h2s[tid] + acc;
    float s = dpp_sum(y), s2 = dpp_sum(y*y);
    float m = s*(1.f/64.f), var = fmaxf(s2*(1.f/64.f) - m*m, 0.f);
    h3s[tid] = (y - m)*rsqrtf(var + 1e-5f)*g3[tid] + be3[tid];
  }
  __syncthreads();
  if (tid < DOUT_){
    const u32* rr = (const u32*)(wr_b + tid*64);
    float acc = br[tid];
    #pragma unroll
    for (int w = 0; w < 32; ++w){ float2 p = bp2(rr[w]); acc += p.x*h3s[2*w] + p.y*h3s[2*w+1]; }
    out[irow*DOUT_ + tid] = acc;
  }
}

extern "C" void kernel_launch(void* const* d_in, const int* in_sizes, int n_in,
                              void* d_out, int out_size, void* d_ws, size_t ws_size,
                              hipStream_t stream){
  const float* audio=(const float*)d_in[0];
  const float* Wa   =(const float*)d_in[1];
  const float* ba   =(const float*)d_in[2];
  const float* objW =(const float*)d_in[3];
  const float* Wq   =(const float*)d_in[4];
  const float* bq   =(const float*)d_in[5];
  const float* Wk   =(const float*)d_in[6];
  const float* bk   =(const float*)d_in[7];
  const float* Wv   =(const float*)d_in[8];
  const float* bv   =(const float*)d_in[9];
  const float* Wo   =(const float*)d_in[10];
  const float* bo   =(const float*)d_in[11];
  const float* Wv2  =(const float*)d_in[12];
  const float* bv2  =(const float*)d_in[13];
  const float* Wo2  =(const float*)d_in[14];
  const float* bo2  =(const float*)d_in[15];
  const float* g1   =(const float*)d_in[16];
  const float* be1  =(const float*)d_in[17];
  const float* g2   =(const float*)d_in[18];
  const float* be2  =(const float*)d_in[19];
  const float* g3   =(const float*)d_in[20];
  const float* be3  =(const float*)d_in[21];
  const float* W1   =(const float*)d_in[22];
  const float* c1   =(const float*)d_in[23];
  const float* W2   =(const float*)d_in[24];
  const float* c2   =(const float*)d_in[25];
  const float* Wr   =(const float*)d_in[26];
  const float* br   =(const float*)d_in[27];
  const float* Wm   =(const float*)d_in[28];
  const float* bm   =(const float*)d_in[29];

  float* ws    = (float*)d_ws;
  float* cross = ws;            // 120*64
  float* xw    = ws + 7680;     // 120*64
  float* Kw    = ws + 15360;    // 120*64
  float* Vw    = ws + 23040;    // 120*64
  u16* bb   = (u16*)(ws + 30720);
  u16* wo_b = bb;               // 4096
  u16* w1_b = bb + 4096;        // 8192
  u16* w2_b = bb + 12288;       // 8192
  u16* wr_b = bb + 20480;       // 1984
  float* out = (float*)d_out;

  k_pre  <<<dim3(121), dim3(256), 0, stream>>>(audio, Wa, ba, Wv2, bv2, Wo2, bo2,
                                               Wo, W1, W2, Wr,
                                               cross, wo_b, w1_b, w2_b, wr_b);
  k_scan <<<dim3(1),   dim3(64),  0, stream>>>(objW, Wq, bq, Wk, bk, Wv, bv, Wo, bo,
                                               g1, be1, g2, be2, g3, be3,
                                               W1, c1, W2, c2, Wr, br, Wm, bm,
                                               cross, xw, Kw, Vw);
  k_final<<<dim3(120), dim3(128), 0, stream>>>(Wq, bq, bo, g1, be1, g2, be2, g3, be3,
                                               c1, c2, br, wo_b, w1_b, w2_b, wr_b,
                                               cross, xw, Kw, Vw, out);
}

// Round 7
// 390.184 us; speedup vs baseline: 1.6221x; 1.6221x over previous
//
#include <hip/hip_runtime.h>

typedef unsigned short u16;
typedef unsigned int   u32;
typedef _Float16 f16;
typedef f16 h2 __attribute__((ext_vector_type(2)));
typedef f16 h4 __attribute__((ext_vector_type(4)));
typedef f16 h8 __attribute__((ext_vector_type(8)));

#define T_    120
#define D_    64
#define DOUT_ 31
#define KROW_ 68    // f16/row: 136B, 8B-aligned
#define VROW_ 132   // f16/row: 264B, 8B-aligned

#if defined(__has_builtin)
#if __has_builtin(__builtin_amdgcn_fdot2)
#define DOT2(a,b,c) __builtin_amdgcn_fdot2((a),(b),(c),false)
#endif
#endif
#ifndef DOT2
#define DOT2(a,b,c) ((float)(a).x*(float)(b).x + ((float)(a).y*(float)(b).y + (c)))
#endif
#define SHV(x,i,j) __builtin_shufflevector((x),(x),(i),(j))

__device__ __forceinline__ h2 pk(float a, float b){
#if defined(__has_builtin) && __has_builtin(__builtin_amdgcn_cvt_pkrtz)
  return __builtin_bit_cast(h2, __builtin_amdgcn_cvt_pkrtz(a, b));
#else
  h2 r; r.x = (f16)a; r.y = (f16)b; return r;
#endif
}
__device__ __forceinline__ float b2f(u16 u){ return __uint_as_float(((u32)u) << 16); }
__device__ __forceinline__ float2 bp2(u32 u){
  float2 r; r.x = __uint_as_float(u << 16); r.y = __uint_as_float(u & 0xffff0000u); return r;
}
__device__ __forceinline__ u16 f2bu(float f){
  u32 u = __float_as_uint(f);
  u32 r = u + 0x7fffu + ((u >> 16) & 1u);
  return (u16)(r >> 16);
}
__device__ __forceinline__ u16 f2h16(float x){
  f16 v = (f16)x; u16 r; __builtin_memcpy(&r, &v, 2); return r;
}
#define WSYNC() do{ __asm__ __volatile__("" ::: "memory"); __builtin_amdgcn_wave_barrier(); }while(0)

__device__ __forceinline__ float dpp_sum(float x){
  int t;
  t = __builtin_amdgcn_update_dpp(0, __float_as_int(x), 0x111, 0xf, 0xf, true); x += __int_as_float(t);
  t = __builtin_amdgcn_update_dpp(0, __float_as_int(x), 0x112, 0xf, 0xf, true); x += __int_as_float(t);
  t = __builtin_amdgcn_update_dpp(0, __float_as_int(x), 0x114, 0xf, 0xf, true); x += __int_as_float(t);
  t = __builtin_amdgcn_update_dpp(0, __float_as_int(x), 0x118, 0xf, 0xf, true); x += __int_as_float(t);
  t = __builtin_amdgcn_update_dpp(0, __float_as_int(x), 0x142, 0xf, 0xf, true); x += __int_as_float(t);
  t = __builtin_amdgcn_update_dpp(0, __float_as_int(x), 0x143, 0xf, 0xf, true); x += __int_as_float(t);
  return __int_as_float(__builtin_amdgcn_readlane(__float_as_int(x), 63));
}
__device__ __forceinline__ float dpp_max_pos(float x){   // requires true max > 0
  int t;
  t = __builtin_amdgcn_update_dpp(0, __float_as_int(x), 0x111, 0xf, 0xf, true); x = fmaxf(x, __int_as_float(t));
  t = __builtin_amdgcn_update_dpp(0, __float_as_int(x), 0x112, 0xf, 0xf, true); x = fmaxf(x, __int_as_float(t));
  t = __builtin_amdgcn_update_dpp(0, __float_as_int(x), 0x114, 0xf, 0xf, true); x = fmaxf(x, __int_as_float(t));
  t = __builtin_amdgcn_update_dpp(0, __float_as_int(x), 0x118, 0xf, 0xf, true); x = fmaxf(x, __int_as_float(t));
  t = __builtin_amdgcn_update_dpp(0, __float_as_int(x), 0x142, 0xf, 0xf, true); x = fmaxf(x, __int_as_float(t));
  t = __builtin_amdgcn_update_dpp(0, __float_as_int(x), 0x143, 0xf, 0xf, true); x = fmaxf(x, __int_as_float(t));
  return __int_as_float(__builtin_amdgcn_readlane(__float_as_int(x), 63));
}
__device__ __forceinline__ float pe_val(int row, int i){
  const float coef = -0.28782313662425574f; // -ln(10000)/32
  int p = row % 10;
  float dv  = __expf((float)(i >> 1) * coef);
  float ang = (float)p * dv;
  return (i & 1) ? __cosf(ang) : __sinf(ang);
}
__device__ __forceinline__ void loadrow32(h2* dst, const float* row){
  #pragma unroll
  for (int r = 0; r < 16; ++r){
    float4 f = ((const float4*)row)[r];
    dst[2*r]   = pk(f.x, f.y);
    dst[2*r+1] = pk(f.z, f.w);
  }
}

// ---------- kernel PRE: blocks 0-119: mem+cross; block 120: bf16 prep + M=Wm@Wr fusion ----------
__global__ __launch_bounds__(256) void k_pre(const float* __restrict__ audio,
                                             const float* __restrict__ Wa, const float* __restrict__ ba,
                                             const float* __restrict__ Wv2, const float* __restrict__ bv2,
                                             const float* __restrict__ Wo2, const float* __restrict__ bo2,
                                             const float* __restrict__ Wo, const float* __restrict__ W1,
                                             const float* __restrict__ W2, const float* __restrict__ Wr,
                                             const float* __restrict__ Wm, const float* __restrict__ br,
                                             const float* __restrict__ bm,
                                             float* __restrict__ cross, float* __restrict__ Ms,
                                             float* __restrict__ bMv,
                                             u16* __restrict__ wob, u16* __restrict__ w1b,
                                             u16* __restrict__ w2b, u16* __restrict__ wrb){
  const int b = blockIdx.x, tid = threadIdx.x;
  if (b == 120){
    for (int i = tid; i < 4096; i += 256) wob[i] = f2bu(Wo[i]);
    for (int i = tid; i < 8192; i += 256){ w1b[i] = f2bu(W1[i]); w2b[i] = f2bu(W2[i]); }
    for (int i = tid; i < 1984; i += 256) wrb[i] = f2bu(Wr[i]);
    for (int idx = tid; idx < 4096; idx += 256){
      int d = idx >> 6, e = idx & 63;
      float acc = 0.f;
      #pragma unroll
      for (int j = 0; j < 31; ++j) acc += Wm[d*31 + j] * Wr[j*64 + e];
      Ms[idx] = acc;
    }
    if (tid < 64){
      float acc = bm[tid];
      #pragma unroll
      for (int j = 0; j < 31; ++j) acc += Wm[tid*31 + j] * br[j];
      bMv[tid] = acc;
    }
    return;
  }
  __shared__ float ash[1024];
  __shared__ float msh[64], tsh[64];
  for (int i = tid; i < 1024; i += 256) ash[i] = audio[b*1024 + i];
  __syncthreads();
  const int w = tid >> 6, lane = tid & 63;
  for (int d = w*16; d < w*16 + 16; ++d){
    const float4* row = (const float4*)(Wa + d*1024);
    float acc = 0.f;
    #pragma unroll
    for (int m = 0; m < 4; ++m){
      float4 wp = row[lane + 64*m];
      int j = 4*(lane + 64*m);
      acc += wp.x*ash[j] + wp.y*ash[j+1] + wp.z*ash[j+2] + wp.w*ash[j+3];
    }
    acc = dpp_sum(acc);
    if (lane == 0) msh[d] = acc + ba[d];
  }
  __syncthreads();
  if (tid < 64){
    const float4* r1 = (const float4*)(Wv2 + tid*64);
    float a = bv2[tid];
    #pragma unroll
    for (int j = 0; j < 16; ++j){ float4 p = r1[j]; a += p.x*msh[4*j] + p.y*msh[4*j+1] + p.z*msh[4*j+2] + p.w*msh[4*j+3]; }
    tsh[tid] = a;
  }
  __syncthreads();
  if (tid < 64){
    const float4* r2 = (const float4*)(Wo2 + tid*64);
    float c = bo2[tid];
    #pragma unroll
    for (int j = 0; j < 16; ++j){ float4 p = r2[j]; c += p.x*tsh[4*j] + p.y*tsh[4*j+1] + p.z*tsh[4*j+2] + p.w*tsh[4*j+3]; }
    cross[b*64 + tid] = c;
  }
}

// ---------- kernel SCAN: 2 waves, no in-loop global ops, balanced register weights ----------
__global__ __launch_bounds__(128, 1) void k_scan(
    const float* __restrict__ objW,
    const float* __restrict__ Wq, const float* __restrict__ bq,
    const float* __restrict__ Wk, const float* __restrict__ bk,
    const float* __restrict__ Wv, const float* __restrict__ bv,
    const float* __restrict__ Wo, const float* __restrict__ bo,
    const float* __restrict__ g1, const float* __restrict__ be1,
    const float* __restrict__ g2, const float* __restrict__ be2,
    const float* __restrict__ g3, const float* __restrict__ be3,
    const float* __restrict__ W1, const float* __restrict__ c1,
    const float* __restrict__ W2, const float* __restrict__ c2,
    const float* __restrict__ Ms, const float* __restrict__ bMv,
    const float* __restrict__ cross,
    u16* __restrict__ xw16, u16* __restrict__ Kw16, u16* __restrict__ Vw16)
{
  __shared__ __align__(16) f16 KcS[128*KROW_];   // 17.0 KB (rows 119..127 stay zero)
  __shared__ __align__(16) f16 VcS[D_*VROW_];    // 16.5 KB
  __shared__ __align__(16) f16 xwS[T_*D_];       // 15.0 KB  x history (f16)
  __shared__ __align__(16) f16 sch[256];
  __shared__ __align__(16) f16 xh[64], qh[64], ath[64], h2h[64], h3h[64];
  __shared__ __align__(16) f16 fsh[128];
  __shared__ float at_p1[64], h2f[64], xf[64];
  __shared__ float pe_tab[640];

  const int tid = threadIdx.x;
  const int i = tid & 63;
  const bool w0 = tid < 64;

  // shared-name register weights:
  //  wave0: A=Wq  B=Wv  C=Wo  D=W1[0:64)     (128 h2)
  //  wave1: A=Wk  B=W1[64:128) C|D=W2 row  E=M row  (160 h2)
  h2 A[32], B[32], C[32], D[32], E[32];
  float biasA=0.f, biasB=0.f, bo_r=0.f, c1r=0.f, c2_r=0.f, bmst=0.f, cls_r=0.f;
  float g1r=0.f,b1r=0.f,g2r=0.f,b2r=0.f,g3r=0.f,b3r=0.f;

  if (w0){
    loadrow32(A, Wq + i*64);
    loadrow32(B, Wv + i*64);
    loadrow32(C, Wo + i*64);
    loadrow32(D, W1 + i*64);
    biasA = bq[i]; biasB = bv[i]; bo_r = bo[i]; c1r = c1[i];
    g1r = g1[i]; b1r = be1[i]; g2r = g2[i]; b2r = be2[i];
    cls_r = cross[119*64 + i];
  } else {
    loadrow32(A, Wk + i*64);
    loadrow32(B, W1 + (64+i)*64);
    loadrow32(C, W2 + i*128);
    loadrow32(D, W2 + i*128 + 64);
    loadrow32(E, Ms + i*64);
    biasA = bk[i]; c1r = c1[64+i]; c2_r = c2[i];
    g3r = g3[i]; b3r = be3[i];
    bmst = bMv[i] + objW[i*5];
  }
  { u32* p = (u32*)KcS; for (int idx = tid; idx < 128*KROW_/2; idx += 128) p[idx] = 0; }
  { u32* p = (u32*)VcS; for (int idx = tid; idx < D_*VROW_/2;  idx += 128) p[idx] = 0; }
  for (int idx = tid; idx < 640; idx += 128) pe_tab[idx] = pe_val(idx >> 6, idx & 63);
  if (w0){
    float st = objW[i*5];
    float x0 = st + pe_val(0, i);
    xf[i] = x0; xh[i] = (f16)x0; xwS[i] = (f16)x0;
  }
  __syncthreads();

  int pp = 1;  // (t+1) % 10
  for (int t = 0; t < T_-1; ++t){
    // ---- P1: wave0 q (A) + v (B) ; wave1 k (A) ----
    {
      const h8* xv = (const h8*)xh;
      if (w0){
        float q0=biasA,q1=0.f,q2=0.f,q3=0.f, v0=biasB,v1=0.f,v2=0.f,v3=0.f;
        #pragma unroll
        for (int r = 0; r < 8; ++r){
          h8 x = xv[r];
          h2 xa=SHV(x,0,1), xb=SHV(x,2,3), xc=SHV(x,4,5), xd=SHV(x,6,7);
          q0 = DOT2(A[4*r+0], xa, q0); q1 = DOT2(A[4*r+1], xb, q1);
          q2 = DOT2(A[4*r+2], xc, q2); q3 = DOT2(A[4*r+3], xd, q3);
          v0 = DOT2(B[4*r+0], xa, v0); v1 = DOT2(B[4*r+1], xb, v1);
          v2 = DOT2(B[4*r+2], xc, v2); v3 = DOT2(B[4*r+3], xd, v3);
        }
        qh[i] = (f16)((q0+q1)+(q2+q3));
        VcS[i*VROW_ + t] = (f16)((v0+v1)+(v2+v3));
      } else {
        float k0=biasA,k1=0.f,k2=0.f,k3=0.f;
        #pragma unroll
        for (int r = 0; r < 8; ++r){
          h8 x = xv[r];
          k0 = DOT2(A[4*r+0], SHV(x,0,1), k0);
          k1 = DOT2(A[4*r+1], SHV(x,2,3), k1);
          k2 = DOT2(A[4*r+2], SHV(x,4,5), k2);
          k3 = DOT2(A[4*r+3], SHV(x,6,7), k3);
        }
        KcS[t*KROW_ + i] = (f16)((k0+k1)+(k2+k3));
      }
    }
    __syncthreads();
    // ---- P2+P3: wave h = head h; scores rows j, j+64; DPP softmax ----
    {
      const int h = tid >> 6, j = i;
      const h8* qv = (const h8*)(qh + h*32);
      const h4* k0 = (const h4*)(KcS + j*KROW_ + h*32);
      const h4* k1 = (const h4*)(KcS + (j+64)*KROW_ + h*32);
      float d0a=0.f,d0b=0.f,d1a=0.f,d1b=0.f;
      #pragma unroll
      for (int r = 0; r < 4; ++r){
        h8 q = qv[r];
        h4 ka = k0[2*r], kb = k0[2*r+1], kc = k1[2*r], kd = k1[2*r+1];
        d0a = DOT2(SHV(ka,0,1), SHV(q,0,1), d0a);
        d0b = DOT2(SHV(ka,2,3), SHV(q,2,3), d0b);
        d0a = DOT2(SHV(kb,0,1), SHV(q,4,5), d0a);
        d0b = DOT2(SHV(kb,2,3), SHV(q,6,7), d0b);
        d1a = DOT2(SHV(kc,0,1), SHV(q,0,1), d1a);
        d1b = DOT2(SHV(kc,2,3), SHV(q,2,3), d1b);
        d1a = DOT2(SHV(kd,0,1), SHV(q,4,5), d1a);
        d1b = DOT2(SHV(kd,2,3), SHV(q,6,7), d1b);
      }
      float d0 = d0a + d0b, d1 = d1a + d1b;
      const float slope = h ? 0.00390625f : 0.0625f;
      int r0 = (t - j) / 10, r1 = (t - j - 64) / 10;
      float s0 = (j      <= t) ? d0*0.17677669529663687f - slope*(float)r0 : -1e30f;
      float s1 = (j + 64 <= t) ? d1*0.17677669529663687f - slope*(float)r1 : -1e30f;
      float m = dpp_max_pos(fmaxf(s0, s1) + 16384.f) - 16384.f;
      float e0 = (j      <= t) ? __expf(s0 - m) : 0.f;
      float e1 = (j + 64 <= t) ? __expf(s1 - m) : 0.f;
      float inv = 1.f / dpp_sum(e0 + e1);
      sch[h*128 + j]      = (f16)(e0*inv);
      sch[h*128 + j + 64] = (f16)(e1*inv);
    }
    __syncthreads();
    // ---- P4: wave0 positions 0..63, wave1 64..119 (pad zero) ----
    float atp0 = 0.f;
    {
      const int hd = i >> 5;
      const h8* av = (const h8*)(sch + hd*128) + (w0 ? 0 : 8);
      const h4* vv = (const h4*)(VcS + i*VROW_) + (w0 ? 0 : 16);
      float p0=0.f,p1=0.f,p2=0.f,p3=0.f;
      #pragma unroll
      for (int r = 0; r < 8; ++r){
        h8 a = av[r];
        h4 va = vv[2*r], vb = vv[2*r+1];
        p0 = DOT2(SHV(va,0,1), SHV(a,0,1), p0);
        p1 = DOT2(SHV(va,2,3), SHV(a,2,3), p1);
        p2 = DOT2(SHV(vb,0,1), SHV(a,4,5), p2);
        p3 = DOT2(SHV(vb,2,3), SHV(a,6,7), p3);
      }
      float p = (p0+p1)+(p2+p3);
      if (!w0) at_p1[i] = p; else atp0 = p;
    }
    __syncthreads();
    // ---- P5 (wave0): combine; sa = at@Wo^T + bo ; LN1 ; +cross_last ; LN2 ----
    if (w0){
      float atv = atp0 + at_p1[i];
      ath[i] = (f16)atv;
      WSYNC();
      const h8* av = (const h8*)ath;
      float a0=bo_r, a1=0.f, a2=0.f, a3=0.f;
      #pragma unroll
      for (int r = 0; r < 8; ++r){
        h8 x = av[r];
        a0 = DOT2(C[4*r+0], SHV(x,0,1), a0);
        a1 = DOT2(C[4*r+1], SHV(x,2,3), a1);
        a2 = DOT2(C[4*r+2], SHV(x,4,5), a2);
        a3 = DOT2(C[4*r+3], SHV(x,6,7), a3);
      }
      float y = xf[i] + (a0+a1)+(a2+a3);
      float s = dpp_sum(y), s2 = dpp_sum(y*y);
      float m = s*(1.f/64.f), var = fmaxf(s2*(1.f/64.f) - m*m, 0.f);
      float h1 = (y - m)*rsqrtf(var + 1e-5f)*g1r + b1r;
      float z = h1 + cls_r;
      float sz = dpp_sum(z), sz2 = dpp_sum(z*z);
      float mz = sz*(1.f/64.f), vz = fmaxf(sz2*(1.f/64.f) - mz*mz, 0.f);
      float h2v = (z - mz)*rsqrtf(vz + 1e-5f)*g2r + b2r;
      h2h[i] = (f16)h2v;
      h2f[i] = h2v;
    }
    __syncthreads();
    // ---- P6: FFN1 both waves (wave0: D = W1 rows 0..63; wave1: B = rows 64..127) ----
    {
      const h8* hv = (const h8*)h2h;
      float a0=c1r, a1=0.f, a2=0.f, a3=0.f;
      if (w0){
        #pragma unroll
        for (int r = 0; r < 8; ++r){
          h8 x = hv[r];
          a0 = DOT2(D[4*r+0], SHV(x,0,1), a0);
          a1 = DOT2(D[4*r+1], SHV(x,2,3), a1);
          a2 = DOT2(D[4*r+2], SHV(x,4,5), a2);
          a3 = DOT2(D[4*r+3], SHV(x,6,7), a3);
        }
      } else {
        #pragma unroll
        for (int r = 0; r < 8; ++r){
          h8 x = hv[r];
          a0 = DOT2(B[4*r+0], SHV(x,0,1), a0);
          a1 = DOT2(B[4*r+1], SHV(x,2,3), a1);
          a2 = DOT2(B[4*r+2], SHV(x,4,5), a2);
          a3 = DOT2(B[4*r+3], SHV(x,6,7), a3);
        }
      }
      fsh[tid] = (f16)fmaxf((a0+a1)+(a2+a3), 0.f);
    }
    __syncthreads();
    // ---- P7+P9 (wave1): FFN2 (C,D) + LN3 ; fused (Wm@Wr) matvec (E) + pe ----
    if (!w0){
      const h8* fv = (const h8*)fsh;
      float a0=c2_r, a1=0.f, a2=0.f, a3=0.f;
      #pragma unroll
      for (int r = 0; r < 8; ++r){
        h8 x = fv[r];
        a0 = DOT2(C[4*r+0], SHV(x,0,1), a0);
        a1 = DOT2(C[4*r+1], SHV(x,2,3), a1);
        a2 = DOT2(C[4*r+2], SHV(x,4,5), a2);
        a3 = DOT2(C[4*r+3], SHV(x,6,7), a3);
      }
      #pragma unroll
      for (int r = 0; r < 8; ++r){
        h8 x = fv[8+r];
        a0 = DOT2(D[4*r+0], SHV(x,0,1), a0);
        a1 = DOT2(D[4*r+1], SHV(x,2,3), a1);
        a2 = DOT2(D[4*r+2], SHV(x,4,5), a2);
        a3 = DOT2(D[4*r+3], SHV(x,6,7), a3);
      }
      float y = h2f[i] + (a0+a1)+(a2+a3);
      float s = dpp_sum(y), s2 = dpp_sum(y*y);
      float m = s*(1.f/64.f), var = fmaxf(s2*(1.f/64.f) - m*m, 0.f);
      float h3v = (y - m)*rsqrtf(var + 1e-5f)*g3r + b3r;
      h3h[i] = (f16)h3v;
      WSYNC();
      const h8* hv3 = (const h8*)h3h;
      float m0=bmst, m1=0.f, m2=0.f, m3=0.f;
      #pragma unroll
      for (int r = 0; r < 8; ++r){
        h8 x = hv3[r];
        m0 = DOT2(E[4*r+0], SHV(x,0,1), m0);
        m1 = DOT2(E[4*r+1], SHV(x,2,3), m1);
        m2 = DOT2(E[4*r+2], SHV(x,4,5), m2);
        m3 = DOT2(E[4*r+3], SHV(x,6,7), m3);
      }
      float xn = (m0+m1)+(m2+m3) + pe_tab[pp*64 + i];
      xf[i] = xn;
      xh[i] = (f16)xn;
      xwS[(t+1)*64 + i] = (f16)xn;
    }
    __syncthreads();
    pp = (pp == 9) ? 0 : pp + 1;
  }
  // ---- epilogue: k,v for row 119 directly to global f16 ----
  {
    const h8* xv = (const h8*)xh;
    if (w0){
      float v0=biasB,v1=0.f,v2=0.f,v3=0.f;
      #pragma unroll
      for (int r = 0; r < 8; ++r){
        h8 x = xv[r];
        v0 = DOT2(B[4*r+0], SHV(x,0,1), v0);
        v1 = DOT2(B[4*r+1], SHV(x,2,3), v1);
        v2 = DOT2(B[4*r+2], SHV(x,4,5), v2);
        v3 = DOT2(B[4*r+3], SHV(x,6,7), v3);
      }
      Vw16[119*64 + i] = f2h16((v0+v1)+(v2+v3));
    } else {
      float k0=biasA,k1=0.f,k2=0.f,k3=0.f;
      #pragma unroll
      for (int r = 0; r < 8; ++r){
        h8 x = xv[r];
        k0 = DOT2(A[4*r+0], SHV(x,0,1), k0);
        k1 = DOT2(A[4*r+1], SHV(x,2,3), k1);
        k2 = DOT2(A[4*r+2], SHV(x,4,5), k2);
        k3 = DOT2(A[4*r+3], SHV(x,6,7), k3);
      }
      Kw16[119*64 + i] = f2h16((k0+k1)+(k2+k3));
    }
  }
  // ---- dump LDS histories (rows 0..118 K/V, all x) ----
  {
    const u16* kc = (const u16*)KcS;
    const u16* vc = (const u16*)VcS;
    for (int idx = tid; idx < 119*64; idx += 128){
      int t_ = idx >> 6, d = idx & 63;
      Kw16[idx] = kc[t_*KROW_ + d];
      Vw16[idx] = vc[d*VROW_ + t_];
    }
    const u32* xs32 = (const u32*)xwS;
    for (int idx = tid; idx < T_*D_/2; idx += 128) ((u32*)xw16)[idx] = xs32[idx];
  }
}

// ---------- kernel FINAL: full pass, one block per row (f16 x/K/V inputs) ----------
__global__ __launch_bounds__(128) void k_final(
    const float* __restrict__ Wq, const float* __restrict__ bq, const float* __restrict__ bo,
    const float* __restrict__ g1, const float* __restrict__ be1,
    const float* __restrict__ g2, const float* __restrict__ be2,
    const float* __restrict__ g3, const float* __restrict__ be3,
    const float* __restrict__ c1, const float* __restrict__ c2, const float* __restrict__ br,
    const u16* __restrict__ wo_b, const u16* __restrict__ w1_b,
    const u16* __restrict__ w2_b, const u16* __restrict__ wr_b,
    const float* __restrict__ cross, const u16* __restrict__ xw16,
    const u16* __restrict__ Kw16, const u16* __restrict__ Vw16,
    float* __restrict__ out)
{
  __shared__ float xs[64], qs[64], at[64], h2s[64], h3s[64], fs[128], sc[256];
  const int irow = blockIdx.x, tid = threadIdx.x;
  const f16* xp = (const f16*)xw16;
  const f16* kp = (const f16*)Kw16;
  const f16* vp = (const f16*)Vw16;
  if (tid < 64) xs[tid] = (float)xp[irow*64 + tid];
  __syncthreads();
  if (tid < 64){
    const float4* wr_ = (const float4*)(Wq + tid*64);
    float acc = bq[tid];
    #pragma unroll
    for (int j = 0; j < 16; ++j){ float4 w = wr_[j]; acc += w.x*xs[4*j] + w.y*xs[4*j+1] + w.z*xs[4*j+2] + w.w*xs[4*j+3]; }
    qs[tid] = acc;
  }
  __syncthreads();
  {
    const int h = tid >> 6, j = tid & 63;
    const float* qh_ = qs + h*32;
    float d0 = 0.f, d1 = 0.f;
    const h4* k0 = (const h4*)(kp + j*64 + h*32);
    #pragma unroll
    for (int w = 0; w < 8; ++w){
      h4 p = k0[w];
      d0 += (float)p.x*qh_[4*w] + (float)p.y*qh_[4*w+1] + (float)p.z*qh_[4*w+2] + (float)p.w*qh_[4*w+3];
    }
    if (j < 56){
      const h4* k1 = (const h4*)(kp + (j+64)*64 + h*32);
      #pragma unroll
      for (int w = 0; w < 8; ++w){
        h4 p = k1[w];
        d1 += (float)p.x*qh_[4*w] + (float)p.y*qh_[4*w+1] + (float)p.z*qh_[4*w+2] + (float)p.w*qh_[4*w+3];
      }
    }
    const float slope = h ? 0.00390625f : 0.0625f;
    float s0 = (j      <= irow) ? d0*0.17677669529663687f - slope*(float)((irow-j)/10)    : -1e30f;
    float s1 = (j + 64 <= irow) ? d1*0.17677669529663687f - slope*(float)((irow-j-64)/10) : -1e30f;
    float m = dpp_max_pos(fmaxf(s0, s1) + 16384.f) - 16384.f;
    float e0 = (j      <= irow) ? __expf(s0 - m) : 0.f;
    float e1 = (j + 64 <= irow) ? __expf(s1 - m) : 0.f;
    float inv = 1.f / dpp_sum(e0 + e1);
    sc[h*128 + j]      = e0*inv;
    sc[h*128 + j + 64] = e1*inv;
  }
  __syncthreads();
  if (tid < 64){
    const float* a = sc + (tid >> 5)*128;
    float a0=0.f,a1=0.f,a2=0.f,a3=0.f;
    #pragma unroll
    for (int jj = 0; jj < 30; ++jj){
      a0 += a[4*jj]   * (float)vp[(4*jj)*64   + tid];
      a1 += a[4*jj+1] * (float)vp[(4*jj+1)*64 + tid];
      a2 += a[4*jj+2] * (float)vp[(4*jj+2)*64 + tid];
      a3 += a[4*jj+3] * (float)vp[(4*jj+3)*64 + tid];
    }
    at[tid] = (a0+a1)+(a2+a3);
  }
  __syncthreads();
  if (tid < 64){
    const u32* orow = (const u32*)(wo_b + tid*64);
    float acc = bo[tid];
    #pragma unroll
    for (int w = 0; w < 32; ++w){ float2 p = bp2(orow[w]); acc += p.x*at[2*w] + p.y*at[2*w+1]; }
    float y = xs[tid] + acc;
    float s = dpp_sum(y), s2 = dpp_sum(y*y);
    float m = s*(1.f/64.f), var = fmaxf(s2*(1.f/64.f) - m*m, 0.f);
    float h1 = (y - m)*rsqrtf(var + 1e-5f)*g1[tid] + be1[tid];
    float z = h1 + cross[irow*64 + tid];
    float sz = dpp_sum(z), sz2 = dpp_sum(z*z);
    float mz = sz*(1.f/64.f), vz = fmaxf(sz2*(1.f/64.f) - mz*mz, 0.f);
    h2s[tid] = (z - mz)*rsqrtf(vz + 1e-5f)*g2[tid] + be2[tid];
  }
  __syncthreads();
  {
    const u32* w1r = (const u32*)(w1_b + tid*64);
    float acc = c1[tid];
    #pragma unroll
    for (int w = 0; w < 32; ++w){ float2 p = bp2(w1r[w]); acc += p.x*h2s[2*w] + p.y*h2s[2*w+1]; }
    fs[tid] = fmaxf(acc, 0.f);
  }
  __syncthreads();
  if (tid < 64){
    const u32* w2r = (const u32*)(w2_b + tid*128);
    float acc = c2[tid];
    #pragma unroll
    for (int w = 0; w < 64; ++w){ float2 p = bp2(w2r[w]); acc += p.x*fs[2*w] + p.y*fs[2*w+1]; }
    float y = h2s[tid] + acc;
    float s = dpp_sum(y), s2 = dpp_sum(y*y);
    float m = s*(1.f/64.f), var = fmaxf(s2*(1.f/64.f) - m*m, 0.f);
    h3s[tid] = (y - m)*rsqrtf(var + 1e-5f)*g3[tid] + be3[tid];
  }
  __syncthreads();
  if (tid < DOUT_){
    const u32* rr = (const u32*)(wr_b + tid*64);
    float acc = br[tid];
    #pragma unroll
    for (int w = 0; w < 32; ++w){ float2 p = bp2(rr[w]); acc += p.x*h3s[2*w] + p.y*h3s[2*w+1]; }
    out[irow*DOUT_ + tid] = acc;
  }
}

extern "C" void kernel_launch(void* const* d_in, const int* in_sizes, int n_in,
                              void* d_out, int out_size, void* d_ws, size_t ws_size,
                              hipStream_t stream){
  const float* audio=(const float*)d_in[0];
  const float* Wa   =(const float*)d_in[1];
  const float* ba   =(const float*)d_in[2];
  const float* objW =(const float*)d_in[3];
  const float* Wq   =(const float*)d_in[4];
  const float* bq   =(const float*)d_in[5];
  const float* Wk   =(const float*)d_in[6];
  const float* bk   =(const float*)d_in[7];
  const float* Wv   =(const float*)d_in[8];
  const float* bv   =(const float*)d_in[9];
  const float* Wo   =(const float*)d_in[10];
  const float* bo   =(const float*)d_in[11];
  const float* Wv2  =(const float*)d_in[12];
  const float* bv2  =(const float*)d_in[13];
  const float* Wo2  =(const float*)d_in[14];
  const float* bo2  =(const float*)d_in[15];
  const float* g1   =(const float*)d_in[16];
  const float* be1  =(const float*)d_in[17];
  const float* g2   =(const float*)d_in[18];
  const float* be2  =(const float*)d_in[19];
  const float* g3   =(const float*)d_in[20];
  const float* be3  =(const float*)d_in[21];
  const float* W1   =(const float*)d_in[22];
  const float* c1   =(const float*)d_in[23];
  const float* W2   =(const float*)d_in[24];
  const float* c2   =(const float*)d_in[25];
  const float* Wr   =(const float*)d_in[26];
  const float* br   =(const float*)d_in[27];
  const float* Wm   =(const float*)d_in[28];
  const float* bm   =(const float*)d_in[29];

  float* ws    = (float*)d_ws;
  float* cross = ws;            // 7680 floats
  float* Ms    = ws + 7680;     // 4096
  float* bMv   = ws + 11776;    // 64
  u16* xw16 = (u16*)(ws + 11840);   // 7680 u16
  u16* Kw16 = xw16 + 7680;
  u16* Vw16 = Kw16 + 7680;
  u16* wo_b = Vw16 + 7680;      // 4096
  u16* w1_b = wo_b + 4096;      // 8192
  u16* w2_b = w1_b + 8192;      // 8192
  u16* wr_b = w2_b + 8192;      // 1984
  float* out = (float*)d_out;

  k_pre  <<<dim3(121), dim3(256), 0, stream>>>(audio, Wa, ba, Wv2, bv2, Wo2, bo2,
                                               Wo, W1, W2, Wr, Wm, br, bm,
                                               cross, Ms, bMv, wo_b, w1_b, w2_b, wr_b);
  k_scan <<<dim3(1),   dim3(128), 0, stream>>>(objW, Wq, bq, Wk, bk, Wv, bv, Wo, bo,
                                               g1, be1, g2, be2, g3, be3,
                                               W1, c1, W2, c2, Ms, bMv,
                                               cross, xw16, Kw16, Vw16);
  k_final<<<dim3(120), dim3(128), 0, stream>>>(Wq, bq, bo, g1, be1, g2, be2, g3, be3,
                                               c1, c2, br, wo_b, w1_b, w2_b, wr_b,
                                               cross, xw16, Kw16, Vw16, out);
}